// Round 2
// baseline (523.478 us; speedup 1.0000x reference)
//
#include <hip/hip_runtime.h>

#define NUM_CLASSES 8

// Lane-pair cooperative argmax:
//   quad index q covers row q/2, half q%2 (4 floats).
//   Lane 2k loads quad (even -> row half [0..3]), lane 2k+1 the next quad
//   (odd -> row half [4..7]) of the SAME row -> loads are fully contiguous
//   across the wave (16 B/lane, 1 KiB per instruction, every 64 B line
//   consumed by exactly one instruction).
__global__ __launch_bounds__(256) void confusion_matrix_kernel(
    const float4* __restrict__ t4,
    const float4* __restrict__ p4,
    float* __restrict__ out,
    int nquads)   // = n_rows * 2
{
    __shared__ unsigned int hist[NUM_CLASSES * NUM_CLASSES];
    if (threadIdx.x < NUM_CLASSES * NUM_CLASSES) hist[threadIdx.x] = 0u;
    __syncthreads();

    const int par = threadIdx.x & 1;      // which half of the row this lane holds
    const int base_off = par * 4;         // global element offset of this half

    const size_t tid = (size_t)blockIdx.x * blockDim.x + threadIdx.x;
    const size_t stride = (size_t)gridDim.x * blockDim.x;
    const int iters = (int)((size_t)nquads / stride);   // full rounds (all lanes in-bounds)

    #pragma unroll 4
    for (int k = 0; k < iters; ++k) {
        const size_t i = tid + (size_t)k * stride;
        float4 tq = t4[i];
        float4 pq = p4[i];

        // local argmax over this half (strict > => first index wins)
        float tm = tq.x; int ti = 0;
        if (tq.y > tm) { tm = tq.y; ti = 1; }
        if (tq.z > tm) { tm = tq.z; ti = 2; }
        if (tq.w > tm) { tm = tq.w; ti = 3; }
        ti += base_off;

        float pm = pq.x; int pi = 0;
        if (pq.y > pm) { pm = pq.y; pi = 1; }
        if (pq.z > pm) { pm = pq.z; pi = 2; }
        if (pq.w > pm) { pm = pq.w; pi = 3; }
        pi += base_off;

        // combine with partner lane (other half of the row); ties -> lower index
        float tom = __shfl_xor(tm, 1);
        int   toi = __shfl_xor(ti, 1);
        if (tom > tm || (tom == tm && toi < ti)) { tm = tom; ti = toi; }

        float pom = __shfl_xor(pm, 1);
        int   poi = __shfl_xor(pi, 1);
        if (pom > pm || (pom == pm && poi < pi)) { pm = pom; pi = poi; }

        if (par == 0) atomicAdd(&hist[ti * NUM_CLASSES + pi], 1u);
    }

    // tail (not taken for 2^24 quads / 2^19 threads, but keep it correct)
    {
        const size_t i = tid + (size_t)iters * stride;
        if (i < (size_t)nquads) {
            float4 tq = t4[i];
            float4 pq = p4[i];
            float tm = tq.x; int ti = 0;
            if (tq.y > tm) { tm = tq.y; ti = 1; }
            if (tq.z > tm) { tm = tq.z; ti = 2; }
            if (tq.w > tm) { tm = tq.w; ti = 3; }
            ti += base_off;
            float pm = pq.x; int pi = 0;
            if (pq.y > pm) { pm = pq.y; pi = 1; }
            if (pq.z > pm) { pm = pq.z; pi = 2; }
            if (pq.w > pm) { pm = pq.w; pi = 3; }
            pi += base_off;
            // nquads is even and pairs are aligned, so the partner lane is
            // active whenever this lane is.
            float tom = __shfl_xor(tm, 1);
            int   toi = __shfl_xor(ti, 1);
            if (tom > tm || (tom == tm && toi < ti)) { tm = tom; ti = toi; }
            float pom = __shfl_xor(pm, 1);
            int   poi = __shfl_xor(pi, 1);
            if (pom > pm || (pom == pm && poi < pi)) { pm = pom; pi = poi; }
            if (par == 0) atomicAdd(&hist[ti * NUM_CLASSES + pi], 1u);
        }
    }

    __syncthreads();
    if (threadIdx.x < NUM_CLASSES * NUM_CLASSES) {
        unsigned int v = hist[threadIdx.x];
        if (v) atomicAdd(&out[threadIdx.x], (float)v);
    }
}

extern "C" void kernel_launch(void* const* d_in, const int* in_sizes, int n_in,
                              void* d_out, int out_size, void* d_ws, size_t ws_size,
                              hipStream_t stream)
{
    const float4* y_true4 = (const float4*)d_in[0];
    const float4* y_pred4 = (const float4*)d_in[1];
    float* out = (float*)d_out;

    const int nquads = in_sizes[0] / 4;   // 2 quads per 8-class row

    // Harness re-poisons d_out with 0xAA before every timed replay: zero it.
    hipMemsetAsync(out, 0, (size_t)out_size * sizeof(float), stream);

    const int block = 256;
    const int grid = 2048;   // 8 blocks/CU resident, 32 quads/thread
    confusion_matrix_kernel<<<grid, block, 0, stream>>>(y_true4, y_pred4, out, nquads);
}